// Round 2
// baseline (169500.098 us; speedup 1.0000x reference)
//
#include <hip/hip_runtime.h>
#include <hip/hip_bf16.h>
#include <cstdint>
#include <cstddef>

// Problem constants
#define BB   64
#define TT   512
#define HH   500
#define G4H  2000   // 4*H
#define KPAD 512    // recurrent K padded 500 -> 512
#define TCH  64     // timesteps per phase
#define D1P  1024   // layer-1 input dim padded 1000 -> 1024
#define NBLK_DIR 250

__device__ __forceinline__ float sigm(float x) { return 1.f / (1.f + __expf(-x)); }
// NaN-safe tanh via exp (saturates cleanly at +-1)
__device__ __forceinline__ float tanh_fast(float x) {
    float e = __expf(2.f * x);
    return 1.f - 2.f / (e + 1.f);
}

// ---- prep: pad W_hh [2000][500] -> [2000][512] (zeros) for 4 (layer,dir) ----
__global__ __launch_bounds__(256) void pad_whh_kernel(
    const float* __restrict__ w0, const float* __restrict__ w1,
    const float* __restrict__ w2, const float* __restrict__ w3,
    float* __restrict__ dst)
{
    int idx = blockIdx.x * 256 + threadIdx.x;   // exactly 4*2000*512 threads
    int k = idx & (KPAD - 1);
    int rowAll = idx >> 9;                      // 0..7999
    int ld = rowAll / G4H;
    int r  = rowAll - ld * G4H;
    const float* src = (ld == 0) ? w0 : (ld == 1) ? w1 : (ld == 2) ? w2 : w3;
    dst[idx] = (k < HH) ? src[r * HH + k] : 0.f;
}

// ---- prep: pad W_ih1 [2000][1000] -> [2000][1024] for 2 dirs ----
__global__ __launch_bounds__(256) void pad_wih1_kernel(
    const float* __restrict__ wf, const float* __restrict__ wb,
    float* __restrict__ dst)
{
    int idx = blockIdx.x * 256 + threadIdx.x;   // exactly 2*2000*1024 threads
    int k = idx & (D1P - 1);
    int rowAll = idx >> 10;                     // 0..3999
    int d = rowAll / G4H;
    int r = rowAll - d * G4H;
    const float* src = d ? wb : wf;
    dst[idx] = (k < 1000) ? src[r * 1000 + k] : 0.f;
}

// ---- input-projection GEMM for one 64-timestep chunk, both dirs ----
// C[64 tl x 2000 n] = A[64 x K] @ W^T + bias, per batch b (blockIdx.x), dir (blockIdx.z)
__global__ __launch_bounds__(256, 3) void gemm_chunk_kernel(
    const float* __restrict__ A, int lda, int K,
    const float* __restrict__ Wf, const float* __restrict__ Wb,
    const float* __restrict__ bf_, const float* __restrict__ bb_,
    float* __restrict__ gates, int t0f, int t0b)
{
    const int dir = blockIdx.z;
    const float* W    = dir ? Wb  : Wf;
    const float* bias = dir ? bb_ : bf_;
    const int t0 = dir ? t0b : t0f;
    const int b  = blockIdx.x;
    const int n_base = blockIdx.y * 32;
    const int tid  = threadIdx.x;
    const int lane = tid & 63;
    const int w = __builtin_amdgcn_readfirstlane(tid >> 6);  // wave id: owns 8 n-rows

    __shared__ float As[64][66];
    __shared__ float Cs[64][36];

    float acc[8];
    #pragma unroll
    for (int i = 0; i < 8; ++i) acc[i] = 0.f;

    const int row0   = b * TT + t0;
    const int mStage = tid >> 2;
    const int kStage = (tid & 3) << 4;

    for (int k0 = 0; k0 < K; k0 += 64) {
        const float* ap = A + (size_t)(row0 + mStage) * lda + k0 + kStage;
        #pragma unroll
        for (int i = 0; i < 16; i += 4) {
            float4 v = *(const float4*)(ap + i);
            *(float2*)&As[mStage][kStage + i]     = make_float2(v.x, v.y);
            *(float2*)&As[mStage][kStage + i + 2] = make_float2(v.z, v.w);
        }
        __syncthreads();
        float a[64];
        #pragma unroll
        for (int i = 0; i < 64; i += 2) {
            float2 v = *(const float2*)&As[lane][i];
            a[i] = v.x; a[i + 1] = v.y;
        }
        __syncthreads();
        #pragma unroll
        for (int q = 0; q < 16; ++q) {
            #pragma unroll
            for (int ni = 0; ni < 8; ++ni) {
                const int row = n_base + w * 8 + ni;
                if (row < G4H) {
                    const float4 w4 = *(const float4*)(W + (size_t)row * K + k0 + q * 4);
                    float s = acc[ni];
                    s = fmaf(w4.x, a[q * 4 + 0], s);
                    s = fmaf(w4.y, a[q * 4 + 1], s);
                    s = fmaf(w4.z, a[q * 4 + 2], s);
                    s = fmaf(w4.w, a[q * 4 + 3], s);
                    acc[ni] = s;
                }
            }
        }
    }

    #pragma unroll
    for (int ni = 0; ni < 8; ++ni) Cs[lane][w * 8 + ni] = acc[ni];
    __syncthreads();
    {
        const int m  = tid >> 2;
        const int nn = (tid & 3) << 3;
        float* gp = gates + (size_t)dir * (BB * TCH * G4H)
                          + (size_t)(b * TCH + m) * G4H + n_base + nn;
        #pragma unroll
        for (int i = 0; i < 8; i += 4) {
            const int n = n_base + nn + i;
            if (n < G4H) {
                float4 v;
                v.x = Cs[m][nn + i + 0] + bias[n + 0];
                v.y = Cs[m][nn + i + 1] + bias[n + 1];
                v.z = Cs[m][nn + i + 2] + bias[n + 2];
                v.w = Cs[m][nn + i + 3] + bias[n + 3];
                *(float4*)(gp + i) = v;
            }
        }
    }
}

// ---- persistent recurrence kernel: one launch = 64 timesteps, both dirs ----
// Blocks 0..249 = fwd, 250..499 = bwd. Block owns 2 hidden units (8 gate rows).
// W_hh slice preloaded to LDS once; c + masked-h carry live in LDS across steps;
// h double-buffered in global by parity; per-dir generation barrier per step.
__global__ __launch_bounds__(256, 2) void lstm_phase_kernel(
    const float* __restrict__ gates,   // [dir][B][TCH][G4H]
    const float* __restrict__ whh,     // layer base of padded [dir][2000][512]
    const int*   __restrict__ lengths,
    float* __restrict__ hbuf,          // [dir][2][B][KPAD]
    float* __restrict__ cbuf,          // [dir][B][KPAD]
    float* __restrict__ yout, int y_ld,
    int s0, int gen_base,
    unsigned int* __restrict__ barrier) // [dir*2+0]=cnt, [dir*2+1]=gen
{
    const int tid  = threadIdx.x;
    const int dir  = (blockIdx.x >= NBLK_DIR) ? 1 : 0;
    const int bi   = blockIdx.x - dir * NBLK_DIR;
    const int u0   = bi * 2;
    const int lane = tid & 63;
    const int kc   = tid >> 6;          // k-quarter 0..3

    __shared__ float wlds[8][512];      // [g*2+j][k]
    __shared__ float red[4][64][9];     // [kc][b][g*2+j], padded stride 9
    __shared__ float ch[2][2][64];      // [c/h][j][b]

    // preload W_hh slice (8 rows x 512) once per phase
    const float* WL = whh + (size_t)dir * G4H * KPAD;
    for (int i = tid; i < 8 * 128; i += 256) {
        const int r  = i >> 7;                 // 0..7 = g*2+j
        const int kk = (i & 127) << 2;
        const int g = r >> 1, j = r & 1;
        *(float4*)&wlds[r][kk] =
            *(const float4*)(WL + (size_t)(g * HH + u0 + j) * KPAD + kk);
    }
    // init carry state
    int len_r = 0;
    if (tid < 128) {
        const int j = tid & 1, b = tid >> 1;
        ch[0][j][b] = cbuf[(size_t)(dir * BB + b) * KPAD + u0 + j];
        ch[1][j][b] = hbuf[((size_t)(dir * 2 + 0) * BB + b) * KPAD + u0 + j]; // s0 even -> par 0
        len_r = lengths[b];
    }
    __syncthreads();

    const float* gbase = gates + (size_t)dir * (BB * TCH * G4H);
    unsigned int* cnt = barrier + dir * 2;
    unsigned int* gen = barrier + dir * 2 + 1;

    for (int sl = 0; sl < TCH; ++sl) {
        const int s   = s0 + sl;
        const int par = s & 1;
        const int t   = dir ? (TT - 1 - s) : s;
        const int tl  = dir ? (TCH - 1 - sl) : sl;

        // prefetch gate-x for this block's units (overlaps with the dot below)
        float gxv[4];
        if (tid < 128) {
            const int j = tid & 1, b = tid >> 1;
            const float* gx = gbase + ((size_t)b * TCH + tl) * G4H + u0 + j;
            #pragma unroll
            for (int g = 0; g < 4; ++g) gxv[g] = gx[g * HH];
        }

        // load full h (this lane's batch, this wave's k-quarter) into VGPRs
        const float* hp = hbuf + ((size_t)(dir * 2 + par) * BB + lane) * KPAD + kc * 128;
        float h[128];
        #pragma unroll
        for (int i = 0; i < 128; i += 4) {
            float4 v = *(const float4*)(hp + i);
            h[i] = v.x; h[i + 1] = v.y; h[i + 2] = v.z; h[i + 3] = v.w;
        }

        // 8 gate-rows x 128 k MACs; weights broadcast from LDS (conflict-free)
        float acc[8];
        #pragma unroll
        for (int r = 0; r < 8; ++r) acc[r] = 0.f;
        #pragma unroll
        for (int r = 0; r < 8; ++r) {
            #pragma unroll
            for (int q = 0; q < 32; ++q) {
                const float4 w4 = *(const float4*)&wlds[r][kc * 128 + q * 4];
                float sa = acc[r];
                sa = fmaf(w4.x, h[q * 4 + 0], sa);
                sa = fmaf(w4.y, h[q * 4 + 1], sa);
                sa = fmaf(w4.z, h[q * 4 + 2], sa);
                sa = fmaf(w4.w, h[q * 4 + 3], sa);
                acc[r] = sa;
            }
        }
        #pragma unroll
        for (int r = 0; r < 8; ++r) red[kc][lane][r] = acc[r];
        __syncthreads();

        if (tid < 128) {
            const int j = tid & 1, b = tid >> 1;
            const int uu = u0 + j;
            float pre[4];
            #pragma unroll
            for (int g = 0; g < 4; ++g) {
                const int r = g * 2 + j;
                pre[g] = (red[0][b][r] + red[1][b][r]) + (red[2][b][r] + red[3][b][r]) + gxv[g];
            }
            const float cold = ch[0][j][b];
            const float hold = ch[1][j][b];
            const float ig = sigm(pre[0]);
            const float fg = sigm(pre[1]);
            const float gg = tanh_fast(pre[2]);
            const float og = sigm(pre[3]);
            const float cn = fg * cold + ig * gg;
            const float hn = og * tanh_fast(cn);
            const bool msk = (t < len_r);
            const float cw = msk ? cn : cold;
            const float hw = msk ? hn : hold;
            ch[0][j][b] = cw;
            ch[1][j][b] = hw;
            hbuf[((size_t)(dir * 2 + (par ^ 1)) * BB + b) * KPAD + uu] = hw;
            yout[((size_t)b * TT + t) * y_ld + dir * HH + uu] = msk ? hn : 0.f;
        }

        // per-dir generation barrier (device scope); also fences red/ch reuse
        __syncthreads();
        if (tid == 0) {
            __threadfence();
            const unsigned int old = atomicAdd(cnt, 1u);
            if (old == (unsigned)(NBLK_DIR - 1)) {
                atomicExch(cnt, 0u);
                __threadfence();
                atomicAdd(gen, 1u);
            } else {
                const unsigned int target = (unsigned)(gen_base + sl + 1);
                while (__hip_atomic_load(gen, __ATOMIC_ACQUIRE, __HIP_MEMORY_SCOPE_AGENT) < target) {
                    __builtin_amdgcn_s_sleep(2);
                }
            }
        }
        __syncthreads();
        __threadfence();
    }

    // persist c for next phase
    if (tid < 128) {
        const int j = tid & 1, b = tid >> 1;
        cbuf[(size_t)(dir * BB + b) * KPAD + u0 + j] = ch[0][j][b];
    }
}

extern "C" void kernel_launch(void* const* d_in, const int* in_sizes, int n_in,
                              void* d_out, int out_size, void* d_ws, size_t ws_size,
                              hipStream_t stream)
{
    (void)in_sizes; (void)n_in; (void)out_size; (void)ws_size;

    const float* seqs    = (const float*)d_in[0];
    const int*   lengths = (const int*)  d_in[1];
    const float* W_ih0f  = (const float*)d_in[2];
    const float* W_hh0f  = (const float*)d_in[3];
    const float* b0f     = (const float*)d_in[4];
    const float* W_ih0b  = (const float*)d_in[5];
    const float* W_hh0b  = (const float*)d_in[6];
    const float* b0b     = (const float*)d_in[7];
    const float* W_ih1f  = (const float*)d_in[8];
    const float* W_hh1f  = (const float*)d_in[9];
    const float* b1f     = (const float*)d_in[10];
    const float* W_ih1b  = (const float*)d_in[11];
    const float* W_hh1b  = (const float*)d_in[12];
    const float* b1b     = (const float*)d_in[13];

    char* ws = (char*)d_ws;
    const size_t SZ_GATES = (size_t)2 * BB * TCH * G4H * 4;       //  65,536,000
    const size_t SZ_OUT0  = (size_t)BB * TT * D1P * 4;            // 134,217,728
    const size_t SZ_WHH   = (size_t)2 * 2 * G4H * KPAD * 4;       //  16,384,000
    const size_t SZ_WIH1  = (size_t)2 * G4H * D1P * 4;            //  16,384,000
    const size_t SZ_HBUF  = (size_t)2 * 2 * BB * KPAD * 4;        //     524,288
    const size_t SZ_CBUF  = (size_t)2 * BB * KPAD * 4;            //     262,144

    float* gatesc  = (float*)(ws);
    float* out0    = (float*)(ws + SZ_GATES);
    float* whhpad  = (float*)(ws + SZ_GATES + SZ_OUT0);
    float* wih1pad = (float*)(ws + SZ_GATES + SZ_OUT0 + SZ_WHH);
    float* hbuf    = (float*)(ws + SZ_GATES + SZ_OUT0 + SZ_WHH + SZ_WIH1);
    float* cbuf    = (float*)(ws + SZ_GATES + SZ_OUT0 + SZ_WHH + SZ_WIH1 + SZ_HBUF);
    unsigned int* barrier =
        (unsigned int*)(ws + SZ_GATES + SZ_OUT0 + SZ_WHH + SZ_WIH1 + SZ_HBUF + SZ_CBUF);

    pad_whh_kernel<<<16000, 256, 0, stream>>>(W_hh0f, W_hh0b, W_hh1f, W_hh1b, whhpad);
    pad_wih1_kernel<<<16000, 256, 0, stream>>>(W_ih1f, W_ih1b, wih1pad);
    hipMemsetAsync(out0, 0, SZ_OUT0, stream);
    hipMemsetAsync(barrier, 0, 4 * sizeof(unsigned int), stream);

    for (int layer = 0; layer < 2; ++layer) {
        hipMemsetAsync(hbuf, 0, SZ_HBUF, stream);
        hipMemsetAsync(cbuf, 0, SZ_CBUF, stream);

        const float* A    = layer ? out0 : seqs;
        const int    lda  = layer ? D1P : 512;
        const int    K    = layer ? D1P : 512;
        const float* Wf   = layer ? wih1pad                      : W_ih0f;
        const float* Wb   = layer ? wih1pad + (size_t)G4H * D1P  : W_ih0b;
        const float* bf_  = layer ? b1f : b0f;
        const float* bb_  = layer ? b1b : b0b;
        const float* whhL = whhpad + (size_t)layer * 2 * G4H * KPAD;
        float*       yo   = layer ? (float*)d_out : out0;
        const int    y_ld = layer ? 1000 : D1P;

        for (int ph = 0; ph < 8; ++ph) {
            const int t0f = ph * TCH;
            const int t0b = TT - TCH * (ph + 1);
            gemm_chunk_kernel<<<dim3(64, 63, 2), 256, 0, stream>>>(
                A, lda, K, Wf, Wb, bf_, bb_, gatesc, t0f, t0b);
            const int lidx = layer * 8 + ph;
            lstm_phase_kernel<<<2 * NBLK_DIR, 256, 0, stream>>>(
                gatesc, whhL, lengths, hbuf, cbuf, yo, y_ld,
                ph * TCH, lidx * TCH, barrier);
        }
    }
}

// Round 3
// 53930.798 us; speedup vs baseline: 3.1429x; 3.1429x over previous
//
#include <hip/hip_runtime.h>
#include <hip/hip_bf16.h>
#include <cstdint>
#include <cstddef>

// Problem constants
#define BB   64
#define TT   512
#define HH   500
#define G4H  2000   // 4*H
#define KPAD 512    // recurrent K padded 500 -> 512
#define TCH  64     // timesteps per phase
#define D1P  1024   // layer-1 input dim padded 1000 -> 1024
#define NBLK_DIR 125

__device__ __forceinline__ float sigm(float x) { return 1.f / (1.f + __expf(-x)); }
// NaN-safe tanh via exp (saturates cleanly at +-1)
__device__ __forceinline__ float tanh_fast(float x) {
    float e = __expf(2.f * x);
    return 1.f - 2.f / (e + 1.f);
}

// ---- prep: pad W_hh [2000][500] -> [2000][512] (zeros) for 4 (layer,dir) ----
__global__ __launch_bounds__(256) void pad_whh_kernel(
    const float* __restrict__ w0, const float* __restrict__ w1,
    const float* __restrict__ w2, const float* __restrict__ w3,
    float* __restrict__ dst)
{
    int idx = blockIdx.x * 256 + threadIdx.x;   // exactly 4*2000*512 threads
    int k = idx & (KPAD - 1);
    int rowAll = idx >> 9;                      // 0..7999
    int ld = rowAll / G4H;
    int r  = rowAll - ld * G4H;
    const float* src = (ld == 0) ? w0 : (ld == 1) ? w1 : (ld == 2) ? w2 : w3;
    dst[idx] = (k < HH) ? src[r * HH + k] : 0.f;
}

// ---- prep: pad W_ih1 [2000][1000] -> [2000][1024] for 2 dirs ----
__global__ __launch_bounds__(256) void pad_wih1_kernel(
    const float* __restrict__ wf, const float* __restrict__ wb,
    float* __restrict__ dst)
{
    int idx = blockIdx.x * 256 + threadIdx.x;   // exactly 2*2000*1024 threads
    int k = idx & (D1P - 1);
    int rowAll = idx >> 10;                     // 0..3999
    int d = rowAll / G4H;
    int r = rowAll - d * G4H;
    const float* src = d ? wb : wf;
    dst[idx] = (k < 1000) ? src[r * 1000 + k] : 0.f;
}

// ---- input-projection GEMM for one 64-timestep chunk, both dirs ----
// C[64 tl x 2000 n] = A[64 x K] @ W^T + bias, per batch b (blockIdx.x), dir (blockIdx.z)
__global__ __launch_bounds__(256, 3) void gemm_chunk_kernel(
    const float* __restrict__ A, int lda, int K,
    const float* __restrict__ Wf, const float* __restrict__ Wb,
    const float* __restrict__ bf_, const float* __restrict__ bb_,
    float* __restrict__ gates, int t0f, int t0b)
{
    const int dir = blockIdx.z;
    const float* W    = dir ? Wb  : Wf;
    const float* bias = dir ? bb_ : bf_;
    const int t0 = dir ? t0b : t0f;
    const int b  = blockIdx.x;
    const int n_base = blockIdx.y * 32;
    const int tid  = threadIdx.x;
    const int lane = tid & 63;
    const int w = __builtin_amdgcn_readfirstlane(tid >> 6);  // wave id: owns 8 n-rows

    __shared__ float As[64][66];
    __shared__ float Cs[64][36];

    float acc[8];
    #pragma unroll
    for (int i = 0; i < 8; ++i) acc[i] = 0.f;

    const int row0   = b * TT + t0;
    const int mStage = tid >> 2;
    const int kStage = (tid & 3) << 4;

    for (int k0 = 0; k0 < K; k0 += 64) {
        const float* ap = A + (size_t)(row0 + mStage) * lda + k0 + kStage;
        #pragma unroll
        for (int i = 0; i < 16; i += 4) {
            float4 v = *(const float4*)(ap + i);
            *(float2*)&As[mStage][kStage + i]     = make_float2(v.x, v.y);
            *(float2*)&As[mStage][kStage + i + 2] = make_float2(v.z, v.w);
        }
        __syncthreads();
        float a[64];
        #pragma unroll
        for (int i = 0; i < 64; i += 2) {
            float2 v = *(const float2*)&As[lane][i];
            a[i] = v.x; a[i + 1] = v.y;
        }
        __syncthreads();
        #pragma unroll
        for (int q = 0; q < 16; ++q) {
            #pragma unroll
            for (int ni = 0; ni < 8; ++ni) {
                const int row = n_base + w * 8 + ni;
                if (row < G4H) {
                    const float4 w4 = *(const float4*)(W + (size_t)row * K + k0 + q * 4);
                    float s = acc[ni];
                    s = fmaf(w4.x, a[q * 4 + 0], s);
                    s = fmaf(w4.y, a[q * 4 + 1], s);
                    s = fmaf(w4.z, a[q * 4 + 2], s);
                    s = fmaf(w4.w, a[q * 4 + 3], s);
                    acc[ni] = s;
                }
            }
        }
    }

    #pragma unroll
    for (int ni = 0; ni < 8; ++ni) Cs[lane][w * 8 + ni] = acc[ni];
    __syncthreads();
    {
        const int m  = tid >> 2;
        const int nn = (tid & 3) << 3;
        float* gp = gates + (size_t)dir * (BB * TCH * G4H)
                          + (size_t)(b * TCH + m) * G4H + n_base + nn;
        #pragma unroll
        for (int i = 0; i < 8; i += 4) {
            const int n = n_base + nn + i;
            if (n < G4H) {
                float4 v;
                v.x = Cs[m][nn + i + 0] + bias[n + 0];
                v.y = Cs[m][nn + i + 1] + bias[n + 1];
                v.z = Cs[m][nn + i + 2] + bias[n + 2];
                v.w = Cs[m][nn + i + 3] + bias[n + 3];
                *(float4*)(gp + i) = v;
            }
        }
    }
}

// ---- persistent recurrence kernel: one launch = 64 timesteps, both dirs ----
// 250 blocks (125/dir, guaranteed co-resident: 1 block/CU). Block owns 4 hidden
// units (16 gate rows). Weights via wave-uniform s_load. All cross-block h
// traffic uses sc0sc1 coherent atomics (RELAXED, AGENT) -> no cache-op fences.
// Barrier: single monotonic counter per dir, relaxed atomics only.
__global__ __launch_bounds__(256, 1) void lstm_phase_kernel(
    const float* __restrict__ gates,   // [dir][B][TCH][G4H]
    const float* __restrict__ whh,     // layer base of padded [dir][2000][512]
    const int*   __restrict__ lengths,
    float* __restrict__ hbuf,          // [dir][2][B][KPAD]
    float* __restrict__ cbuf,          // [dir][B][KPAD]
    float* __restrict__ yout, int y_ld,
    int s0, unsigned int tgt0,
    unsigned int* __restrict__ barrier) // [dir] monotonic arrival counter
{
    const int tid  = threadIdx.x;
    const int dir  = (blockIdx.x >= NBLK_DIR) ? 1 : 0;
    const int bi   = blockIdx.x - dir * NBLK_DIR;
    const int u0   = bi * 4;
    const int lane = tid & 63;
    const int kc   = __builtin_amdgcn_readfirstlane(tid >> 6);  // k-quarter 0..3

    __shared__ float red[4][64][20];   // [kc][b][r], stride 20 keeps b128 alignment
    __shared__ float ch[2][4][64];     // [c/h][j][b]

    const float* WL = whh + (size_t)dir * G4H * KPAD;
    // wave-uniform row base pointers (SGPR-resident)
    const float* wp[16];
    #pragma unroll
    for (int r = 0; r < 16; ++r)
        wp[r] = WL + (size_t)((r >> 2) * HH + u0 + (r & 3)) * KPAD + kc * 128;

    // epilogue identity for this thread: (batch, unit j)
    const int eb = tid >> 2;
    const int ej = tid & 3;
    const int len_r = lengths[eb];

    // init carry state (cross-dispatch: kernel-boundary coherence, plain loads ok)
    ch[0][ej][eb] = cbuf[(size_t)(dir * BB + eb) * KPAD + u0 + ej];
    ch[1][ej][eb] = hbuf[((size_t)(dir * 2 + 0) * BB + eb) * KPAD + u0 + ej]; // s0 even -> par 0
    __syncthreads();

    const float* gbase = gates + (size_t)dir * (BB * TCH * G4H);
    unsigned int* cnt = barrier + dir;

    for (int sl = 0; sl < TCH; ++sl) {
        const int s   = s0 + sl;
        const int par = s & 1;
        const int t   = dir ? (TT - 1 - s) : s;
        const int tl  = dir ? (TCH - 1 - sl) : sl;

        // prefetch gate-x for this thread's (b, unit) — plain loads (same-dispatch
        // producer is an earlier dispatch; coherent via kernel-boundary release)
        float gxv[4];
        {
            const float* gx = gbase + ((size_t)eb * TCH + tl) * G4H + u0 + ej;
            #pragma unroll
            for (int g = 0; g < 4; ++g) gxv[g] = gx[g * HH];
        }

        // load h (lane = batch, wave = k-quarter) via coherent 8B atomic loads
        float h[128];
        {
            const unsigned long long* hp8 = (const unsigned long long*)
                (hbuf + ((size_t)(dir * 2 + par) * BB + lane) * KPAD + kc * 128);
            #pragma unroll
            for (int i = 0; i < 64; ++i) {
                unsigned long long v = __hip_atomic_load(hp8 + i, __ATOMIC_RELAXED,
                                                         __HIP_MEMORY_SCOPE_AGENT);
                h[2 * i]     = __uint_as_float((unsigned int)(v & 0xffffffffull));
                h[2 * i + 1] = __uint_as_float((unsigned int)(v >> 32));
            }
        }

        // 16 gate-rows x 128 k MACs; weights via wave-uniform s_load_dwordx4
        float acc[16];
        #pragma unroll
        for (int r = 0; r < 16; ++r) acc[r] = 0.f;
        #pragma unroll
        for (int q = 0; q < 32; ++q) {
            #pragma unroll
            for (int r = 0; r < 16; ++r) {
                const float4 w4 = *(const float4*)(wp[r] + q * 4);
                float sa = acc[r];
                sa = fmaf(w4.x, h[q * 4 + 0], sa);
                sa = fmaf(w4.y, h[q * 4 + 1], sa);
                sa = fmaf(w4.z, h[q * 4 + 2], sa);
                sa = fmaf(w4.w, h[q * 4 + 3], sa);
                acc[r] = sa;
            }
        }
        #pragma unroll
        for (int r = 0; r < 16; r += 4)
            *(float4*)&red[kc][lane][r] = make_float4(acc[r], acc[r+1], acc[r+2], acc[r+3]);
        __syncthreads();

        // epilogue: every thread owns one (batch, unit)
        {
            float pre[4];
            #pragma unroll
            for (int g = 0; g < 4; ++g) {
                const int r = g * 4 + ej;
                pre[g] = (red[0][eb][r] + red[1][eb][r])
                       + (red[2][eb][r] + red[3][eb][r]) + gxv[g];
            }
            const float cold = ch[0][ej][eb];
            const float hold = ch[1][ej][eb];
            const float ig = sigm(pre[0]);
            const float fg = sigm(pre[1]);
            const float gg = tanh_fast(pre[2]);
            const float og = sigm(pre[3]);
            const float cn = fg * cold + ig * gg;
            const float hn = og * tanh_fast(cn);
            const bool msk = (t < len_r);
            const float cw = msk ? cn : cold;
            const float hw = msk ? hn : hold;
            ch[0][ej][eb] = cw;
            ch[1][ej][eb] = hw;
            // coherent h publish (sc0sc1 store, completes at IF before barrier add)
            __hip_atomic_store(
                hbuf + ((size_t)(dir * 2 + (par ^ 1)) * BB + eb) * KPAD + u0 + ej,
                hw, __ATOMIC_RELAXED, __HIP_MEMORY_SCOPE_AGENT);
            yout[((size_t)eb * TT + t) * y_ld + dir * HH + u0 + ej] = msk ? hn : 0.f;
        }

        // fence-free barrier: compiler drains vmcnt before s_barrier, so the
        // sc-stores above are globally visible before the arrival add.
        __syncthreads();
        if (tid == 0) {
            __hip_atomic_fetch_add(cnt, 1u, __ATOMIC_RELAXED, __HIP_MEMORY_SCOPE_AGENT);
            const unsigned int tgt = tgt0 + (unsigned int)(sl + 1) * NBLK_DIR;
            while (__hip_atomic_load(cnt, __ATOMIC_RELAXED, __HIP_MEMORY_SCOPE_AGENT) < tgt) {
                __builtin_amdgcn_s_sleep(4);
            }
        }
        __syncthreads();
    }

    // persist c for next phase (plain store; kernel-boundary release)
    cbuf[(size_t)(dir * BB + eb) * KPAD + u0 + ej] = ch[0][ej][eb];
}

extern "C" void kernel_launch(void* const* d_in, const int* in_sizes, int n_in,
                              void* d_out, int out_size, void* d_ws, size_t ws_size,
                              hipStream_t stream)
{
    (void)in_sizes; (void)n_in; (void)out_size; (void)ws_size;

    const float* seqs    = (const float*)d_in[0];
    const int*   lengths = (const int*)  d_in[1];
    const float* W_ih0f  = (const float*)d_in[2];
    const float* W_hh0f  = (const float*)d_in[3];
    const float* b0f     = (const float*)d_in[4];
    const float* W_ih0b  = (const float*)d_in[5];
    const float* W_hh0b  = (const float*)d_in[6];
    const float* b0b     = (const float*)d_in[7];
    const float* W_ih1f  = (const float*)d_in[8];
    const float* W_hh1f  = (const float*)d_in[9];
    const float* b1f     = (const float*)d_in[10];
    const float* W_ih1b  = (const float*)d_in[11];
    const float* W_hh1b  = (const float*)d_in[12];
    const float* b1b     = (const float*)d_in[13];

    char* ws = (char*)d_ws;
    const size_t SZ_GATES = (size_t)2 * BB * TCH * G4H * 4;       //  65,536,000
    const size_t SZ_OUT0  = (size_t)BB * TT * D1P * 4;            // 134,217,728
    const size_t SZ_WHH   = (size_t)2 * 2 * G4H * KPAD * 4;       //  16,384,000
    const size_t SZ_WIH1  = (size_t)2 * G4H * D1P * 4;            //  16,384,000
    const size_t SZ_HBUF  = (size_t)2 * 2 * BB * KPAD * 4;        //     524,288
    const size_t SZ_CBUF  = (size_t)2 * BB * KPAD * 4;            //     262,144

    float* gatesc  = (float*)(ws);
    float* out0    = (float*)(ws + SZ_GATES);
    float* whhpad  = (float*)(ws + SZ_GATES + SZ_OUT0);
    float* wih1pad = (float*)(ws + SZ_GATES + SZ_OUT0 + SZ_WHH);
    float* hbuf    = (float*)(ws + SZ_GATES + SZ_OUT0 + SZ_WHH + SZ_WIH1);
    float* cbuf    = (float*)(ws + SZ_GATES + SZ_OUT0 + SZ_WHH + SZ_WIH1 + SZ_HBUF);
    unsigned int* barrier =
        (unsigned int*)(ws + SZ_GATES + SZ_OUT0 + SZ_WHH + SZ_WIH1 + SZ_HBUF + SZ_CBUF);

    pad_whh_kernel<<<16000, 256, 0, stream>>>(W_hh0f, W_hh0b, W_hh1f, W_hh1b, whhpad);
    pad_wih1_kernel<<<16000, 256, 0, stream>>>(W_ih1f, W_ih1b, wih1pad);
    hipMemsetAsync(out0, 0, SZ_OUT0, stream);
    hipMemsetAsync(barrier, 0, 2 * sizeof(unsigned int), stream);

    for (int layer = 0; layer < 2; ++layer) {
        hipMemsetAsync(hbuf, 0, SZ_HBUF, stream);
        hipMemsetAsync(cbuf, 0, SZ_CBUF, stream);

        const float* A    = layer ? out0 : seqs;
        const int    lda  = layer ? D1P : 512;
        const int    K    = layer ? D1P : 512;
        const float* Wf   = layer ? wih1pad                      : W_ih0f;
        const float* Wb   = layer ? wih1pad + (size_t)G4H * D1P  : W_ih0b;
        const float* bf_  = layer ? b1f : b0f;
        const float* bb_  = layer ? b1b : b0b;
        const float* whhL = whhpad + (size_t)layer * 2 * G4H * KPAD;
        float*       yo   = layer ? (float*)d_out : out0;
        const int    y_ld = layer ? 1000 : D1P;

        for (int ph = 0; ph < 8; ++ph) {
            const int t0f = ph * TCH;
            const int t0b = TT - TCH * (ph + 1);
            gemm_chunk_kernel<<<dim3(64, 63, 2), 256, 0, stream>>>(
                A, lda, K, Wf, Wb, bf_, bb_, gatesc, t0f, t0b);
            const unsigned int tgt0 = (unsigned int)(layer * TT + ph * TCH) * NBLK_DIR;
            lstm_phase_kernel<<<2 * NBLK_DIR, 256, 0, stream>>>(
                gatesc, whhL, lengths, hbuf, cbuf, yo, y_ld,
                ph * TCH, tgt0, barrier);
        }
    }
}

// Round 4
// 26759.793 us; speedup vs baseline: 6.3341x; 2.0154x over previous
//
#include <hip/hip_runtime.h>
#include <hip/hip_bf16.h>
#include <cstdint>
#include <cstddef>

// Problem constants
#define BB   64
#define TT   512
#define HH   500
#define G4H  2000   // 4*H
#define KPAD 512    // recurrent K padded 500 -> 512
#define TCH  64     // timesteps per phase
#define D1P  1024   // layer-1 input dim padded 1000 -> 1024
#define NBLK_DIR 125
#define WSLICE (125 * 16 * 512)   // per-dir fp16 weight slice elements

typedef _Float16 v8h __attribute__((ext_vector_type(8)));
typedef float    v4f __attribute__((ext_vector_type(4)));

union F16x8 {
    unsigned long long u[2];
    float4 f4;
    v8h h;
};

__device__ __forceinline__ float sigm(float x) { return 1.f / (1.f + __expf(-x)); }
__device__ __forceinline__ float tanh_fast(float x) {
    float e = __expf(2.f * x);
    return 1.f - 2.f / (e + 1.f);
}

// ---- prep: W_hh [2000][500] fp32 -> fp16 MFMA-friendly slices ----
// dst[((ld*125 + bi)*16 + n)*512 + k] = fp16(W_hh[ld][g*500 + bi*4 + j][k])
// with n = g*4+j, k<500 else 0.  ld = layer*2+dir.
__global__ __launch_bounds__(256) void pad_whh16_kernel(
    const float* __restrict__ w0, const float* __restrict__ w1,
    const float* __restrict__ w2, const float* __restrict__ w3,
    _Float16* __restrict__ dst)
{
    int idx = blockIdx.x * 256 + threadIdx.x;   // exactly 4*125*16*512 threads
    int k = idx & 511;
    int t = idx >> 9;
    int n = t & 15;  t >>= 4;                   // t in 0..499
    int bi = t % 125;
    int ld = t / 125;
    int g = n >> 2, j = n & 3;
    const float* src = (ld == 0) ? w0 : (ld == 1) ? w1 : (ld == 2) ? w2 : w3;
    float val = (k < HH) ? src[(g * HH + bi * 4 + j) * HH + k] : 0.f;
    dst[idx] = (_Float16)val;
}

// ---- prep: pad W_ih1 [2000][1000] -> [2000][1024] ----
__global__ __launch_bounds__(256) void pad_wih1_kernel(
    const float* __restrict__ wf, const float* __restrict__ wb,
    float* __restrict__ dst)
{
    int idx = blockIdx.x * 256 + threadIdx.x;   // exactly 2*2000*1024 threads
    int k = idx & (D1P - 1);
    int rowAll = idx >> 10;
    int d = rowAll / G4H;
    int r = rowAll - d * G4H;
    const float* src = d ? wb : wf;
    dst[idx] = (k < 1000) ? src[r * 1000 + k] : 0.f;
}

// ---- input-projection GEMM for one 64-timestep chunk, both dirs ----
__global__ __launch_bounds__(256, 3) void gemm_chunk_kernel(
    const float* __restrict__ A, int lda, int K,
    const float* __restrict__ Wf, const float* __restrict__ Wb,
    const float* __restrict__ bf_, const float* __restrict__ bb_,
    float* __restrict__ gates, int t0f, int t0b)
{
    const int dir = blockIdx.z;
    const float* W    = dir ? Wb  : Wf;
    const float* bias = dir ? bb_ : bf_;
    const int t0 = dir ? t0b : t0f;
    const int b  = blockIdx.x;
    const int n_base = blockIdx.y * 32;
    const int tid  = threadIdx.x;
    const int lane = tid & 63;
    const int w = __builtin_amdgcn_readfirstlane(tid >> 6);

    __shared__ float As[64][66];
    __shared__ float Cs[64][36];

    float acc[8];
    #pragma unroll
    for (int i = 0; i < 8; ++i) acc[i] = 0.f;

    const int row0   = b * TT + t0;
    const int mStage = tid >> 2;
    const int kStage = (tid & 3) << 4;

    for (int k0 = 0; k0 < K; k0 += 64) {
        const float* ap = A + (size_t)(row0 + mStage) * lda + k0 + kStage;
        #pragma unroll
        for (int i = 0; i < 16; i += 4) {
            float4 v = *(const float4*)(ap + i);
            *(float2*)&As[mStage][kStage + i]     = make_float2(v.x, v.y);
            *(float2*)&As[mStage][kStage + i + 2] = make_float2(v.z, v.w);
        }
        __syncthreads();
        float a[64];
        #pragma unroll
        for (int i = 0; i < 64; i += 2) {
            float2 v = *(const float2*)&As[lane][i];
            a[i] = v.x; a[i + 1] = v.y;
        }
        __syncthreads();
        #pragma unroll
        for (int q = 0; q < 16; ++q) {
            #pragma unroll
            for (int ni = 0; ni < 8; ++ni) {
                const int row = n_base + w * 8 + ni;
                if (row < G4H) {
                    const float4 w4 = *(const float4*)(W + (size_t)row * K + k0 + q * 4);
                    float s = acc[ni];
                    s = fmaf(w4.x, a[q * 4 + 0], s);
                    s = fmaf(w4.y, a[q * 4 + 1], s);
                    s = fmaf(w4.z, a[q * 4 + 2], s);
                    s = fmaf(w4.w, a[q * 4 + 3], s);
                    acc[ni] = s;
                }
            }
        }
    }

    #pragma unroll
    for (int ni = 0; ni < 8; ++ni) Cs[lane][w * 8 + ni] = acc[ni];
    __syncthreads();
    {
        const int m  = tid >> 2;
        const int nn = (tid & 3) << 3;
        float* gp = gates + (size_t)dir * (BB * TCH * G4H)
                          + (size_t)(b * TCH + m) * G4H + n_base + nn;
        #pragma unroll
        for (int i = 0; i < 8; i += 4) {
            const int n = n_base + nn + i;
            if (n < G4H) {
                float4 v;
                v.x = Cs[m][nn + i + 0] + bias[n + 0];
                v.y = Cs[m][nn + i + 1] + bias[n + 1];
                v.z = Cs[m][nn + i + 2] + bias[n + 2];
                v.w = Cs[m][nn + i + 3] + bias[n + 3];
                *(float4*)(gp + i) = v;
            }
        }
    }
}

// ---- persistent MFMA recurrence: one launch = 64 timesteps, both dirs ----
// 250 blocks (125/dir, 1 block/CU). Block owns 4 hidden units = 16 gate rows
// (N=16). Per step: C[64b x 16n] = h16[64 x 512] @ Wslice^T via 16 mfma
// 16x16x32_f16 per wave (k-split over 4 waves), W frags VGPR-resident for the
// whole phase. h exchanged as fp16 via sc0sc1 coherent atomics. fp32 everywhere
// else (acc, gates, c, y). Barrier: monotonic relaxed counter per dir.
__global__ __launch_bounds__(256, 1) void lstm_phase_kernel(
    const float*    __restrict__ gates,   // [dir][B][TCH][G4H]
    const _Float16* __restrict__ whh16,   // layer base: [dir][bi][16][512]
    const int*      __restrict__ lengths,
    _Float16* __restrict__ h16,           // [dir][2][B][512] fp16
    float*    __restrict__ cbuf,          // [dir][B][KPAD] fp32
    float*    __restrict__ yout, int y_ld,
    int s0, unsigned int tgt0,
    unsigned int* __restrict__ barrier)
{
    const int tid  = threadIdx.x;
    const int dir  = (blockIdx.x >= NBLK_DIR) ? 1 : 0;
    const int bi   = blockIdx.x - dir * NBLK_DIR;
    const int u0   = bi * 4;
    const int lane = tid & 63;
    const int kc   = __builtin_amdgcn_readfirstlane(tid >> 6);  // k-quarter

    __shared__ float redC[4][4][16][17];        // [kc][mt][m][n] (+1 pad)
    __shared__ float ch[2][4][64];              // [c/h fp32][j][b]
    __shared__ unsigned short hsh[4][64];       // fp16 bits of new h [j][b]

    // B fragments: W slice rows n=lane&15, k = kc*128 + kt*32 + (lane>>4)*8 + j
    v8h bfr[4];
    {
        const _Float16* wbase = whh16 + (size_t)dir * WSLICE
            + ((size_t)bi * 16 + (lane & 15)) * 512 + kc * 128 + ((lane >> 4) * 8);
        #pragma unroll
        for (int kt = 0; kt < 4; ++kt) {
            F16x8 f; f.f4 = *(const float4*)(wbase + kt * 32);
            bfr[kt] = f.h;
        }
    }

    // epilogue identity: thread = (batch eb, unit j)
    const int eb = tid >> 2;
    const int ej = tid & 3;
    const int len_r = lengths[eb];

    // carry init (kernel-boundary coherence: plain loads fine)
    ch[0][ej][eb] = cbuf[(size_t)(dir * BB + eb) * KPAD + u0 + ej];
    ch[1][ej][eb] = (float)h16[((size_t)(dir * 2 + 0) * BB + eb) * 512 + u0 + ej];
    __syncthreads();

    const float* gbase = gates + (size_t)dir * (BB * TCH * G4H);
    unsigned int* cnt = barrier + dir;

    for (int sl = 0; sl < TCH; ++sl) {
        const int s   = s0 + sl;
        const int par = s & 1;
        const int t   = dir ? (TT - 1 - s) : s;
        const int tl  = dir ? (TCH - 1 - sl) : sl;

        // gate-x prefetch (fp32, plain)
        float gxv[4];
        {
            const float* gx = gbase + ((size_t)eb * TCH + tl) * G4H + u0 + ej;
            #pragma unroll
            for (int g = 0; g < 4; ++g) gxv[g] = gx[g * HH];
        }

        // A fragments: h16[mt*16 + (lane&15)][kc*128 + kt*32 + (lane>>4)*8 ..+7]
        // via 2x coherent b64 atomic loads each (32 independent loads in flight)
        F16x8 av[4][4];
        {
            const char* habase = (const char*)(h16 + (size_t)(dir * 2 + par) * BB * 512);
            const int rowoff = (lane & 15) * 512 + kc * 128 + ((lane >> 4) * 8);
            #pragma unroll
            for (int mt = 0; mt < 4; ++mt) {
                #pragma unroll
                for (int kt = 0; kt < 4; ++kt) {
                    const size_t off = ((size_t)(mt * 16) * 512 + rowoff + kt * 32) * 2;
                    const unsigned long long* p = (const unsigned long long*)(habase + off);
                    av[mt][kt].u[0] = __hip_atomic_load(p,     __ATOMIC_RELAXED, __HIP_MEMORY_SCOPE_AGENT);
                    av[mt][kt].u[1] = __hip_atomic_load(p + 1, __ATOMIC_RELAXED, __HIP_MEMORY_SCOPE_AGENT);
                }
            }
        }

        // 16 MFMAs: 4 independent acc chains (mt), depth 4 (kt)
        v4f acc[4];
        #pragma unroll
        for (int mt = 0; mt < 4; ++mt) acc[mt] = (v4f)(0.f);
        #pragma unroll
        for (int kt = 0; kt < 4; ++kt) {
            #pragma unroll
            for (int mt = 0; mt < 4; ++mt) {
                acc[mt] = __builtin_amdgcn_mfma_f32_16x16x32_f16(
                    av[mt][kt].h, bfr[kt], acc[mt], 0, 0, 0);
            }
        }

        // k-split partial C tiles -> LDS  (D: m=(lane>>4)*4+i, n=lane&15)
        #pragma unroll
        for (int mt = 0; mt < 4; ++mt) {
            #pragma unroll
            for (int i = 0; i < 4; ++i)
                redC[kc][mt][(lane >> 4) * 4 + i][lane & 15] = acc[mt][i];
        }
        __syncthreads();

        // epilogue: thread owns (batch eb, unit j)
        {
            const int mt = eb >> 4, m = eb & 15;
            float pre[4];
            #pragma unroll
            for (int g = 0; g < 4; ++g) {
                const int n = g * 4 + ej;
                pre[g] = (redC[0][mt][m][n] + redC[1][mt][m][n])
                       + (redC[2][mt][m][n] + redC[3][mt][m][n]) + gxv[g];
            }
            const float cold = ch[0][ej][eb];
            const float hold = ch[1][ej][eb];
            const float ig = sigm(pre[0]);
            const float fg = sigm(pre[1]);
            const float gg = tanh_fast(pre[2]);
            const float og = sigm(pre[3]);
            const float cn = fg * cold + ig * gg;
            const float hn = og * tanh_fast(cn);
            const bool msk = (t < len_r);
            const float cw = msk ? cn : cold;
            const float hw = msk ? hn : hold;
            ch[0][ej][eb] = cw;
            ch[1][ej][eb] = hw;
            const _Float16 hw16 = (_Float16)hw;
            hsh[ej][eb] = *(const unsigned short*)&hw16;
            yout[((size_t)eb * TT + t) * y_ld + dir * HH + u0 + ej] = msk ? hn : 0.f;
        }
        __syncthreads();   // hsh ready; redC reads done

        // publish h as fp16 pairs (coherent b32 stores), even-j threads only
        if ((ej & 1) == 0) {
            const unsigned int pk = (unsigned int)hsh[ej][eb]
                                  | ((unsigned int)hsh[ej + 1][eb] << 16);
            unsigned int* dst = (unsigned int*)
                (h16 + ((size_t)(dir * 2 + (par ^ 1)) * BB + eb) * 512 + u0 + ej);
            __hip_atomic_store(dst, pk, __ATOMIC_RELAXED, __HIP_MEMORY_SCOPE_AGENT);
        }

        // barrier: syncthreads drains the stores (vmcnt(0) before s_barrier),
        // then one arrival atomic + relaxed spin per block.
        __syncthreads();
        if (tid == 0) {
            __hip_atomic_fetch_add(cnt, 1u, __ATOMIC_RELAXED, __HIP_MEMORY_SCOPE_AGENT);
            const unsigned int tgt = tgt0 + (unsigned int)(sl + 1) * NBLK_DIR;
            while (__hip_atomic_load(cnt, __ATOMIC_RELAXED, __HIP_MEMORY_SCOPE_AGENT) < tgt) {
                __builtin_amdgcn_s_sleep(8);
            }
        }
        __syncthreads();
    }

    // persist c (fp32) for next phase
    cbuf[(size_t)(dir * BB + eb) * KPAD + u0 + ej] = ch[0][ej][eb];
}

extern "C" void kernel_launch(void* const* d_in, const int* in_sizes, int n_in,
                              void* d_out, int out_size, void* d_ws, size_t ws_size,
                              hipStream_t stream)
{
    (void)in_sizes; (void)n_in; (void)out_size; (void)ws_size;

    const float* seqs    = (const float*)d_in[0];
    const int*   lengths = (const int*)  d_in[1];
    const float* W_ih0f  = (const float*)d_in[2];
    const float* W_hh0f  = (const float*)d_in[3];
    const float* b0f     = (const float*)d_in[4];
    const float* W_ih0b  = (const float*)d_in[5];
    const float* W_hh0b  = (const float*)d_in[6];
    const float* b0b     = (const float*)d_in[7];
    const float* W_ih1f  = (const float*)d_in[8];
    const float* W_hh1f  = (const float*)d_in[9];
    const float* b1f     = (const float*)d_in[10];
    const float* W_ih1b  = (const float*)d_in[11];
    const float* W_hh1b  = (const float*)d_in[12];
    const float* b1b     = (const float*)d_in[13];

    char* ws = (char*)d_ws;
    const size_t SZ_GATES = (size_t)2 * BB * TCH * G4H * 4;       //  65,536,000
    const size_t SZ_OUT0  = (size_t)BB * TT * D1P * 4;            // 134,217,728
    const size_t SZ_WIH1  = (size_t)2 * G4H * D1P * 4;            //  16,384,000
    const size_t SZ_WHH16 = (size_t)4 * WSLICE * 2;               //   8,192,000
    const size_t SZ_H16   = (size_t)2 * 2 * BB * 512 * 2;         //     262,144
    const size_t SZ_CBUF  = (size_t)2 * BB * KPAD * 4;            //     262,144

    float*     gatesc  = (float*)(ws);
    float*     out0    = (float*)(ws + SZ_GATES);
    float*     wih1pad = (float*)(ws + SZ_GATES + SZ_OUT0);
    _Float16*  whh16   = (_Float16*)(ws + SZ_GATES + SZ_OUT0 + SZ_WIH1);
    _Float16*  h16     = (_Float16*)(ws + SZ_GATES + SZ_OUT0 + SZ_WIH1 + SZ_WHH16);
    float*     cbuf    = (float*)(ws + SZ_GATES + SZ_OUT0 + SZ_WIH1 + SZ_WHH16 + SZ_H16);
    unsigned int* barrier = (unsigned int*)
        (ws + SZ_GATES + SZ_OUT0 + SZ_WIH1 + SZ_WHH16 + SZ_H16 + SZ_CBUF);

    pad_whh16_kernel<<<16000, 256, 0, stream>>>(W_hh0f, W_hh0b, W_hh1f, W_hh1b, whh16);
    pad_wih1_kernel<<<16000, 256, 0, stream>>>(W_ih1f, W_ih1b, wih1pad);
    hipMemsetAsync(out0, 0, SZ_OUT0, stream);
    hipMemsetAsync(barrier, 0, 2 * sizeof(unsigned int), stream);

    for (int layer = 0; layer < 2; ++layer) {
        hipMemsetAsync(h16, 0, SZ_H16, stream);
        hipMemsetAsync(cbuf, 0, SZ_CBUF, stream);

        const float* A    = layer ? out0 : seqs;
        const int    lda  = layer ? D1P : 512;
        const int    K    = layer ? D1P : 512;
        const float* Wf   = layer ? wih1pad                      : W_ih0f;
        const float* Wb   = layer ? wih1pad + (size_t)G4H * D1P  : W_ih0b;
        const float* bf_  = layer ? b1f : b0f;
        const float* bb_  = layer ? b1b : b0b;
        const _Float16* whhL = whh16 + (size_t)layer * 2 * WSLICE;
        float*       yo   = layer ? (float*)d_out : out0;
        const int    y_ld = layer ? 1000 : D1P;

        for (int ph = 0; ph < 8; ++ph) {
            const int t0f = ph * TCH;
            const int t0b = TT - TCH * (ph + 1);
            gemm_chunk_kernel<<<dim3(64, 63, 2), 256, 0, stream>>>(
                A, lda, K, Wf, Wb, bf_, bb_, gatesc, t0f, t0b);
            const unsigned int tgt0 = (unsigned int)(layer * TT + ph * TCH) * NBLK_DIR;
            lstm_phase_kernel<<<2 * NBLK_DIR, 256, 0, stream>>>(
                gatesc, whhL, lengths, h16, cbuf, yo, y_ld,
                ph * TCH, tgt0, barrier);
        }
    }
}